// Round 15
// baseline (569.605 us; speedup 1.0000x reference)
//
#include <hip/hip_runtime.h>
#include <math.h>

#define Bn  8
#define SQn 2048
#define SKn 2048
#define Hn  256
#define NHn 4
#define HDn 64
#define SCALE2 0.1803368801111f   /* 0.125 * log2(e) */

typedef __attribute__((ext_vector_type(4))) float f32x4;
typedef __attribute__((ext_vector_type(4))) unsigned int u32x4;
typedef __attribute__((ext_vector_type(8))) short short8;
typedef unsigned short ushort_t;
typedef unsigned long long ull_t;

__device__ __forceinline__ unsigned short f2bf(float f) {
  unsigned u = __builtin_bit_cast(unsigned, f);
  u += 0x7fffu + ((u >> 16) & 1u);
  return (unsigned short)(u >> 16);
}

__device__ __forceinline__ float fexp2(float x) {
  return __builtin_amdgcn_exp2f(x);
}

__device__ __forceinline__ float bf2f(unsigned short v) {
  unsigned u = (unsigned)v << 16;
  return __builtin_bit_cast(float, u);
}

__device__ __forceinline__ short8 load8f(const float* p) {
  float4 v0 = *(const float4*)p;
  float4 v1 = *(const float4*)(p + 4);
  short8 r;
  r[0] = (short)f2bf(v0.x); r[1] = (short)f2bf(v0.y);
  r[2] = (short)f2bf(v0.z); r[3] = (short)f2bf(v0.w);
  r[4] = (short)f2bf(v1.x); r[5] = (short)f2bf(v1.y);
  r[6] = (short)f2bf(v1.z); r[7] = (short)f2bf(v1.w);
  return r;
}

__device__ __forceinline__ f32x4 mfma16(short8 a, short8 b, f32x4 c) {
  return __builtin_amdgcn_mfma_f32_16x16x32_bf16(a, b, c, 0, 0, 0);
}

// ---------------- prep: W f32->bf16 (once) + mask -> packed bitwords
__global__ __launch_bounds__(256) void prep_kernel(
    const void* __restrict__ maskp,
    const float* __restrict__ Wq, const float* __restrict__ Wk,
    const float* __restrict__ Wv, const float* __restrict__ Wo,
    ull_t* __restrict__ mout, ushort_t* __restrict__ Wb)
{
  const int bid = blockIdx.x;
  if (bid < 16) {
    const int g = bid * 256 + threadIdx.x;       // 4096 threads
    #pragma unroll
    for (int it = 0; it < 8; ++it) {
      const int grp = g + it * 4096;             // 32768 short8-groups total
      const int w = grp >> 13;                   // 8192 groups per matrix
      const int off = (grp & 8191) * 8;
      const float* src = w == 0 ? Wq : w == 1 ? Wk : w == 2 ? Wv : Wo;
      *(short8*)(Wb + w * 65536 + off) = load8f(src + off);
    }
    return;
  }
  const int l = threadIdx.x & 63;
  const unsigned probe = ((const unsigned*)maskp)[l];
  const int isbyte = __any(probe > 1u);
  const int gwave = ((bid - 16) * 256 + threadIdx.x) >> 6;
  const int nwaves = (gridDim.x - 16) * 4;
  const long long total4 = (long long)Bn * SQn * (SKn / 256);  // 4-word groups
  if (isbyte) {
    for (long long w = gwave; w < total4; w += nwaves) {
      const unsigned char* mp = (const unsigned char*)maskp + w * 256;
      bool n0 = mp[l] != 0,        n1 = mp[64 + l] != 0;
      bool n2 = mp[128 + l] != 0,  n3 = mp[192 + l] != 0;
      ull_t b0 = __ballot(n0), b1 = __ballot(n1);
      ull_t b2 = __ballot(n2), b3 = __ballot(n3);
      if (l == 0) {
        mout[w * 4] = b0; mout[w * 4 + 1] = b1;
        mout[w * 4 + 2] = b2; mout[w * 4 + 3] = b3;
      }
    }
  } else {
    for (long long w = gwave; w < total4; w += nwaves) {
      const int* mp = (const int*)maskp + w * 256;
      bool n0 = mp[l] != 0,        n1 = mp[64 + l] != 0;
      bool n2 = mp[128 + l] != 0,  n3 = mp[192 + l] != 0;
      ull_t b0 = __ballot(n0), b1 = __ballot(n1);
      ull_t b2 = __ballot(n2), b3 = __ballot(n3);
      if (l == 0) {
        mout[w * 4] = b0; mout[w * 4 + 1] = b1;
        mout[w * 4 + 2] = b2; mout[w * 4 + 3] = b3;
      }
    }
  }
}

// ------------------------------------- fused Q/K/V projection GEMMs
__global__ __launch_bounds__(256) void proj3_kernel(
    const float* __restrict__ Xq, const float* __restrict__ Xk,
    const float* __restrict__ Xv, const ushort_t* __restrict__ Wb,
    const float* __restrict__ bqp, const float* __restrict__ bkp,
    const float* __restrict__ bvp,
    ushort_t* __restrict__ Qb, ushort_t* __restrict__ Kb,
    ushort_t* __restrict__ Vt)
{
  const int which = blockIdx.z;
  const float* X = which == 0 ? Xq : which == 1 ? Xk : Xv;
  const ushort_t* W = Wb + which * 65536;
  const float* bias = which == 0 ? bqp : which == 1 ? bkp : bvp;
  ushort_t* Y = which == 0 ? Qb : which == 1 ? Kb : Vt;
  const int vtrans = (which == 2);

  const int m0 = blockIdx.x * 64;
  const int n0 = blockIdx.y * 64;
  const int wv = threadIdx.x >> 6;
  const int l  = threadIdx.x & 63;
  const int lr = l & 15, lg = l >> 4;
  const int mrow = m0 + wv * 16 + lr;

  f32x4 acc[4];
  #pragma unroll
  for (int t = 0; t < 4; ++t) acc[t] = (f32x4){0.f, 0.f, 0.f, 0.f};

  const float* ap = X + (size_t)mrow * Hn + lg * 8;
  for (int k0 = 0; k0 < Hn; k0 += 32) {
    short8 a = load8f(ap + k0);
    #pragma unroll
    for (int t = 0; t < 4; ++t) {
      short8 bb = *(const short8*)(W + (size_t)(n0 + t * 16 + lr) * Hn + k0 + lg * 8);
      acc[t] = mfma16(a, bb, acc[t]);
    }
  }

  #pragma unroll
  for (int t = 0; t < 4; ++t) {
    const int n = n0 + t * 16 + lr;
    const float bv = bias[n];
    const int h = n >> 6, d = n & 63;
    if (!vtrans) {
      #pragma unroll
      for (int r = 0; r < 4; ++r) {
        const int m = m0 + wv * 16 + lg * 4 + r;
        const int bb = m >> 11, s = m & 2047;
        size_t idx = (((size_t)bb * NHn + h) * SQn + s) * HDn + d;
        Y[idx] = f2bf(acc[t][r] + bv);
      }
    } else {
      const int m = m0 + wv * 16 + lg * 4;
      const int bb = m >> 11, s = m & 2047;
      ushort4 pk;
      pk.x = f2bf(acc[t][0] + bv); pk.y = f2bf(acc[t][1] + bv);
      pk.z = f2bf(acc[t][2] + bv); pk.w = f2bf(acc[t][3] + bv);
      size_t idx = (((size_t)bb * NHn + h) * HDn + d) * (size_t)SKn + s;
      *(ushort4*)(Y + idx) = pk;
    }
  }
}

// ------------------------------------------- single-pass fused attention
// R15: p-hat is no longer carried in registers (R9's pf8[8] = 32 VGPRs was
// the occupancy blocker: need >102 <=128 regs -> 44% occupancy cap).
// Phase A stores UNNORMALIZED p-hat f32 straight to attn_out (transient
// pack pf feeds PV in the same chunk); Phase B re-reads attn (L2-resident,
// same thread & addresses -> program-order safe) and scales in place by
// rinv. Live set ~80-88 regs -> waves_per_eu(6,6): 85-reg budget, 3
// blocks/CU = 24 waves = 75% occupancy (vs 44%).
__global__ __launch_bounds__(512)
__attribute__((amdgpu_waves_per_eu(6, 6)))
void fused_attn_kernel(
    const ushort_t* __restrict__ Qb, const ushort_t* __restrict__ Kb,
    const ushort_t* __restrict__ Vt, const unsigned* __restrict__ maskbits,
    float* __restrict__ attn_out, ushort_t* __restrict__ Ob)
{
  __shared__ float red[8][16];
  __shared__ float Opart[8][16][66];  // +2 pad kills bank conflicts

  const int bid = blockIdx.x;
  const int rt = (bid & 7) * 512 + (bid >> 3);  // XCD-chunked bijection
  const int wv = threadIdx.x >> 6;
  const int l  = threadIdx.x & 63;
  const int lr = l & 15, lg = l >> 4;
  const int bh = rt >> 7;
  const int q0 = (rt & 127) << 4;
  const int b  = bh >> 2, h = bh & 3;
  const int colbase = wv * 256;

  const ushort_t* Qh = Qb + (size_t)bh * SQn * HDn;
  const ushort_t* Kh = Kb + (size_t)bh * SKn * HDn;
  const ushort_t* Vh = Vt + (size_t)bh * HDn * SKn;

  short8 qa0 = *(const short8*)(Qh + (q0 + lr) * HDn + lg * 8);
  short8 qa1 = *(const short8*)(Qh + (q0 + lr) * HDn + 32 + lg * 8);

  const int krA = (lr >> 2) * 8 + (lr & 3);
  const unsigned* mrow = maskbits + ((size_t)b * SQn + q0 + lr) * (SKn / 32) + wv * 8;
  const int bsh = lg * 8;

  float* arow = attn_out + ((size_t)bh * SQn + q0 + lr) * (size_t)SKn;

  // ---- Phase A: QK^T once; p-hat -> attn (unnormalized) + row-sum + PV
  float lsum = 0.f;
  f32x4 oacc[4];
  #pragma unroll
  for (int dt = 0; dt < 4; ++dt) oacc[dt] = (f32x4){0.f, 0.f, 0.f, 0.f};

  u32x4 mw = *(const u32x4*)mrow;   // second half loaded at s8==4
  #pragma unroll
  for (int s8 = 0; s8 < 8; ++s8) {
    if (s8 == 4) mw = *(const u32x4*)(mrow + 4);
    const int c = colbase + s8 * 32;
    const ushort_t* kp = Kh + (size_t)(c + krA) * HDn + lg * 8;
    short8 ka0 = *(const short8*)(kp);
    short8 ka1 = *(const short8*)(kp + 32);
    short8 kb0 = *(const short8*)(kp + 4 * HDn);
    short8 kb1 = *(const short8*)(kp + 4 * HDn + 32);
    f32x4 za = (f32x4){0.f, 0.f, 0.f, 0.f}, zb = (f32x4){0.f, 0.f, 0.f, 0.f};
    za = mfma16(ka0, qa0, za); za = mfma16(ka1, qa1, za);
    zb = mfma16(kb0, qa0, zb); zb = mfma16(kb1, qa1, zb);

    // V loads issued here: K regs dead, exp/pack VALU below hides latency
    const ushort_t* vp = Vh + (size_t)lr * SKn + c + lg * 8;
    short8 vb0 = *(const short8*)(vp);
    short8 vb1 = *(const short8*)(vp + 16 * SKn);
    short8 vb2 = *(const short8*)(vp + 32 * SKn);
    short8 vb3 = *(const short8*)(vp + 48 * SKn);

    const unsigned bits = (mw[s8 & 3] >> bsh) & 0xFFu;
    float pa0 = ((bits >> 0) & 1) ? fexp2(za[0] * SCALE2) : 0.f;
    float pa1 = ((bits >> 1) & 1) ? fexp2(za[1] * SCALE2) : 0.f;
    float pa2 = ((bits >> 2) & 1) ? fexp2(za[2] * SCALE2) : 0.f;
    float pa3 = ((bits >> 3) & 1) ? fexp2(za[3] * SCALE2) : 0.f;
    float pb0 = ((bits >> 4) & 1) ? fexp2(zb[0] * SCALE2) : 0.f;
    float pb1 = ((bits >> 5) & 1) ? fexp2(zb[1] * SCALE2) : 0.f;
    float pb2 = ((bits >> 6) & 1) ? fexp2(zb[2] * SCALE2) : 0.f;
    float pb3 = ((bits >> 7) & 1) ? fexp2(zb[3] * SCALE2) : 0.f;
    lsum += (pa0 + pa1 + pa2 + pa3) + (pb0 + pb1 + pb2 + pb3);

    // unnormalized p-hat to attn (rescaled in place in Phase B)
    *(f32x4*)(arow + c + lg * 8)     = (f32x4){pa0, pa1, pa2, pa3};
    *(f32x4*)(arow + c + lg * 8 + 4) = (f32x4){pb0, pb1, pb2, pb3};

    short8 pf;   // transient: consumed by PV this chunk
    pf[0] = (short)f2bf(pa0); pf[1] = (short)f2bf(pa1);
    pf[2] = (short)f2bf(pa2); pf[3] = (short)f2bf(pa3);
    pf[4] = (short)f2bf(pb0); pf[5] = (short)f2bf(pb1);
    pf[6] = (short)f2bf(pb2); pf[7] = (short)f2bf(pb3);
    oacc[0] = mfma16(pf, vb0, oacc[0]);
    oacc[1] = mfma16(pf, vb1, oacc[1]);
    oacc[2] = mfma16(pf, vb2, oacc[2]);
    oacc[3] = mfma16(pf, vb3, oacc[3]);
  }

  // row-sum across the 4 lane-groups sharing row lr; stash partial O
  lsum += __shfl_xor(lsum, 16);
  lsum += __shfl_xor(lsum, 32);
  if (l < 16) red[wv][lr] = lsum;
  #pragma unroll
  for (int dt = 0; dt < 4; ++dt)
    #pragma unroll
    for (int r = 0; r < 4; ++r)
      Opart[wv][lg * 4 + r][dt * 16 + lr] = oacc[dt][r];
  __syncthreads();

  float gsum = 0.f;
  #pragma unroll
  for (int ww = 0; ww < 8; ++ww) gsum += red[ww][lr];
  const bool rowempty = (gsum == 0.f);   // fully-masked row (exact)
  const float rinv = rowempty ? 0.f : 1.f / gsum;

  // ---- Phase B: in-place scale attn by rinv (same thread, same addresses)
  #pragma unroll
  for (int s8 = 0; s8 < 8; ++s8) {
    const int c = colbase + s8 * 32;
    f32x4 wa = *(const f32x4*)(arow + c + lg * 8);
    f32x4 wb = *(const f32x4*)(arow + c + lg * 8 + 4);
    #pragma unroll
    for (int j = 0; j < 4; ++j) { wa[j] *= rinv; wb[j] *= rinv; }
    if (rowempty && s8 == 0 && wv == 0 && lg == 0) wa[0] = 1.f;  // one-hot key 0
    *(f32x4*)(arow + c + lg * 8)     = wa;
    *(f32x4*)(arow + c + lg * 8 + 4) = wb;
  }

  // ---- epilogue: cross-wave O reduce, scale by 1/gsum per row
  #pragma unroll
  for (int e = threadIdx.x; e < 1024; e += 512) {
    const int row = e >> 6, d = e & 63;
    float gs = 0.f;
    #pragma unroll
    for (int ww = 0; ww < 8; ++ww) gs += red[ww][row];
    float s = 0.f;
    #pragma unroll
    for (int ww = 0; ww < 8; ++ww) s += Opart[ww][row][d];
    float val;
    if (gs == 0.f) {  // fully-masked row: attn=one-hot(key0) -> O=V[:,0]
      val = bf2f(Vh[(size_t)d * SKn]);
    } else {
      val = s / gs;
    }
    Ob[((size_t)b * SQn + q0 + row) * Hn + h * HDn + d] = f2bf(val);
  }
}

// ------------------------------------------------ output projection (bf16 A,W)
__global__ __launch_bounds__(256) void oproj_kernel(
    const unsigned short* __restrict__ A, const ushort_t* __restrict__ Wob,
    const float* __restrict__ bias, float* __restrict__ out)
{
  const int m0 = blockIdx.x * 64;
  const int n0 = blockIdx.y * 64;
  const int wv = threadIdx.x >> 6;
  const int l  = threadIdx.x & 63;
  const int lr = l & 15, lg = l >> 4;
  const int mrow = m0 + wv * 16 + lr;

  f32x4 acc[4];
  #pragma unroll
  for (int t = 0; t < 4; ++t) acc[t] = (f32x4){0.f, 0.f, 0.f, 0.f};

  for (int k0 = 0; k0 < Hn; k0 += 32) {
    short8 a = *(const short8*)(A + (size_t)mrow * Hn + k0 + lg * 8);
    #pragma unroll
    for (int t = 0; t < 4; ++t) {
      short8 bb = *(const short8*)(Wob + (size_t)(n0 + t * 16 + lr) * Hn + k0 + lg * 8);
      acc[t] = mfma16(a, bb, acc[t]);
    }
  }
  #pragma unroll
  for (int t = 0; t < 4; ++t) {
    const int n = n0 + t * 16 + lr;
    const float bv = bias[n];
    #pragma unroll
    for (int r = 0; r < 4; ++r) {
      const int m = m0 + wv * 16 + lg * 4 + r;
      out[(size_t)m * Hn + n] = acc[t][r] + bv;
    }
  }
}

extern "C" void kernel_launch(void* const* d_in, const int* in_sizes, int n_in,
                              void* d_out, int out_size, void* d_ws, size_t ws_size,
                              hipStream_t stream) {
  const float* query = (const float*)d_in[0];
  const float* key_  = (const float*)d_in[1];
  const float* value = (const float*)d_in[2];
  const void*  mask  = d_in[3];
  const float* Wq = (const float*)d_in[4];
  const float* bq = (const float*)d_in[5];
  const float* Wk = (const float*)d_in[6];
  const float* bk = (const float*)d_in[7];
  const float* Wv = (const float*)d_in[8];
  const float* bv = (const float*)d_in[9];
  const float* Wo = (const float*)d_in[10];
  const float* bo = (const float*)d_in[11];

  float* out  = (float*)d_out;
  float* attn = out + (size_t)Bn * SQn * Hn;

  char* ws = (char*)d_ws;
  unsigned short* Qb = (unsigned short*)ws;
  unsigned short* Kb = Qb + (size_t)Bn * SQn * Hn;
  unsigned short* Vt = Kb + (size_t)Bn * SKn * Hn;
  unsigned short* Ob = Vt + (size_t)Bn * SKn * Hn;
  unsigned* mbits = (unsigned*)(Ob + (size_t)Bn * SQn * Hn);     // 4 MiB
  ushort_t* Wb = (ushort_t*)(mbits + (size_t)Bn * SQn * (SKn / 32));  // 512 KiB

  prep_kernel<<<1040, 256, 0, stream>>>(mask, Wq, Wk, Wv, Wo,
                                        (ull_t*)mbits, Wb);
  proj3_kernel<<<dim3(256, 4, 3), 256, 0, stream>>>(
      query, key_, value, Wb, bq, bk, bv, Qb, Kb, Vt);
  fused_attn_kernel<<<4096, 512, 0, stream>>>(Qb, Kb, Vt, mbits, attn, Ob);
  oproj_kernel<<<dim3(256, 4), 256, 0, stream>>>(Ob, Wb + 3 * 65536, bo, out);
}

// Round 16
// 458.670 us; speedup vs baseline: 1.2419x; 1.2419x over previous
//
#include <hip/hip_runtime.h>
#include <math.h>

#define Bn  8
#define SQn 2048
#define SKn 2048
#define Hn  256
#define NHn 4
#define HDn 64
#define SCALE2 0.1803368801111f   /* 0.125 * log2(e) */

typedef __attribute__((ext_vector_type(4))) float f32x4;
typedef __attribute__((ext_vector_type(4))) unsigned int u32x4;
typedef __attribute__((ext_vector_type(8))) short short8;
typedef unsigned short ushort_t;
typedef unsigned long long ull_t;

__device__ __forceinline__ unsigned short f2bf(float f) {
  unsigned u = __builtin_bit_cast(unsigned, f);
  u += 0x7fffu + ((u >> 16) & 1u);
  return (unsigned short)(u >> 16);
}

__device__ __forceinline__ float fexp2(float x) {
  return __builtin_amdgcn_exp2f(x);
}

__device__ __forceinline__ float bf2f(unsigned short v) {
  unsigned u = (unsigned)v << 16;
  return __builtin_bit_cast(float, u);
}

__device__ __forceinline__ short8 load8f(const float* p) {
  float4 v0 = *(const float4*)p;
  float4 v1 = *(const float4*)(p + 4);
  short8 r;
  r[0] = (short)f2bf(v0.x); r[1] = (short)f2bf(v0.y);
  r[2] = (short)f2bf(v0.z); r[3] = (short)f2bf(v0.w);
  r[4] = (short)f2bf(v1.x); r[5] = (short)f2bf(v1.y);
  r[6] = (short)f2bf(v1.z); r[7] = (short)f2bf(v1.w);
  return r;
}

__device__ __forceinline__ f32x4 mfma16(short8 a, short8 b, f32x4 c) {
  return __builtin_amdgcn_mfma_f32_16x16x32_bf16(a, b, c, 0, 0, 0);
}

// ---- prep: W f32->bf16 + X (q,k,v inputs) f32->bf16 + mask -> bitwords
// Blocks [0,16): Wq,Wk,Wv,Wo -> Wb (4 x 65536).
// Blocks [16,784): query,key,value -> Xb (3 x 4194304) -- kills proj3's
//   4x redundant f32 re-read + cvt (X re-read is bf16 & L3-hot after this).
// Blocks [784,1808): maskbits, 4 independent ballot chains per iter.
__global__ __launch_bounds__(256) void prep_kernel(
    const void* __restrict__ maskp,
    const float* __restrict__ Wq, const float* __restrict__ Wk,
    const float* __restrict__ Wv, const float* __restrict__ Wo,
    const float* __restrict__ Xq, const float* __restrict__ Xk,
    const float* __restrict__ Xv,
    ull_t* __restrict__ mout, ushort_t* __restrict__ Wb,
    ushort_t* __restrict__ Xb)
{
  const int bid = blockIdx.x;
  if (bid < 16) {
    const int g = bid * 256 + threadIdx.x;       // 4096 threads
    #pragma unroll
    for (int it = 0; it < 8; ++it) {
      const int grp = g + it * 4096;             // 32768 short8-groups total
      const int w = grp >> 13;                   // 8192 groups per matrix
      const int off = (grp & 8191) * 8;
      const float* src = w == 0 ? Wq : w == 1 ? Wk : w == 2 ? Wv : Wo;
      *(short8*)(Wb + w * 65536 + off) = load8f(src + off);
    }
    return;
  }
  if (bid < 784) {
    const int g0 = (bid - 16) * 2048 + threadIdx.x;
    #pragma unroll
    for (int it = 0; it < 8; ++it) {
      const int grp = g0 + it * 256;             // 1572864 groups total
      const int w = grp >> 19;                   // 524288 groups per matrix
      const int off = (grp & 524287) * 8;
      const float* src = w == 0 ? Xq : w == 1 ? Xk : Xv;
      *(short8*)(Xb + (size_t)w * 4194304 + off) = load8f(src + off);
    }
    return;
  }
  const int l = threadIdx.x & 63;
  const unsigned probe = ((const unsigned*)maskp)[l];
  const int isbyte = __any(probe > 1u);
  const int gwave = ((bid - 784) * 256 + threadIdx.x) >> 6;
  const int nwaves = (gridDim.x - 784) * 4;
  const long long total4 = (long long)Bn * SQn * (SKn / 256);  // 4-word groups
  if (isbyte) {
    for (long long w = gwave; w < total4; w += nwaves) {
      const unsigned char* mp = (const unsigned char*)maskp + w * 256;
      bool n0 = mp[l] != 0,        n1 = mp[64 + l] != 0;
      bool n2 = mp[128 + l] != 0,  n3 = mp[192 + l] != 0;
      ull_t b0 = __ballot(n0), b1 = __ballot(n1);
      ull_t b2 = __ballot(n2), b3 = __ballot(n3);
      if (l == 0) {
        mout[w * 4] = b0; mout[w * 4 + 1] = b1;
        mout[w * 4 + 2] = b2; mout[w * 4 + 3] = b3;
      }
    }
  } else {
    for (long long w = gwave; w < total4; w += nwaves) {
      const int* mp = (const int*)maskp + w * 256;
      bool n0 = mp[l] != 0,        n1 = mp[64 + l] != 0;
      bool n2 = mp[128 + l] != 0,  n3 = mp[192 + l] != 0;
      ull_t b0 = __ballot(n0), b1 = __ballot(n1);
      ull_t b2 = __ballot(n2), b3 = __ballot(n3);
      if (l == 0) {
        mout[w * 4] = b0; mout[w * 4 + 1] = b1;
        mout[w * 4 + 2] = b2; mout[w * 4 + 3] = b3;
      }
    }
  }
}

// ------------------------------------- fused Q/K/V projection GEMMs
// W and X both pre-converted to bf16 -> pure short8 loads, no cvt VALU.
__global__ __launch_bounds__(256) void proj3_kernel(
    const ushort_t* __restrict__ Xb, const ushort_t* __restrict__ Wb,
    const float* __restrict__ bqp, const float* __restrict__ bkp,
    const float* __restrict__ bvp,
    ushort_t* __restrict__ Qb, ushort_t* __restrict__ Kb,
    ushort_t* __restrict__ Vt)
{
  const int which = blockIdx.z;
  const ushort_t* X = Xb + (size_t)which * 4194304;
  const ushort_t* W = Wb + which * 65536;
  const float* bias = which == 0 ? bqp : which == 1 ? bkp : bvp;
  ushort_t* Y = which == 0 ? Qb : which == 1 ? Kb : Vt;
  const int vtrans = (which == 2);

  const int m0 = blockIdx.x * 64;
  const int n0 = blockIdx.y * 64;
  const int wv = threadIdx.x >> 6;
  const int l  = threadIdx.x & 63;
  const int lr = l & 15, lg = l >> 4;
  const int mrow = m0 + wv * 16 + lr;

  f32x4 acc[4];
  #pragma unroll
  for (int t = 0; t < 4; ++t) acc[t] = (f32x4){0.f, 0.f, 0.f, 0.f};

  const ushort_t* ap = X + (size_t)mrow * Hn + lg * 8;
  for (int k0 = 0; k0 < Hn; k0 += 32) {
    short8 a = *(const short8*)(ap + k0);
    #pragma unroll
    for (int t = 0; t < 4; ++t) {
      short8 bb = *(const short8*)(W + (size_t)(n0 + t * 16 + lr) * Hn + k0 + lg * 8);
      acc[t] = mfma16(a, bb, acc[t]);
    }
  }

  #pragma unroll
  for (int t = 0; t < 4; ++t) {
    const int n = n0 + t * 16 + lr;
    const float bv = bias[n];
    const int h = n >> 6, d = n & 63;
    if (!vtrans) {
      #pragma unroll
      for (int r = 0; r < 4; ++r) {
        const int m = m0 + wv * 16 + lg * 4 + r;
        const int bb = m >> 11, s = m & 2047;
        size_t idx = (((size_t)bb * NHn + h) * SQn + s) * HDn + d;
        Y[idx] = f2bf(acc[t][r] + bv);
      }
    } else {
      const int m = m0 + wv * 16 + lg * 4;
      const int bb = m >> 11, s = m & 2047;
      ushort4 pk;
      pk.x = f2bf(acc[t][0] + bv); pk.y = f2bf(acc[t][1] + bv);
      pk.z = f2bf(acc[t][2] + bv); pk.w = f2bf(acc[t][3] + bv);
      size_t idx = (((size_t)bb * NHn + h) * HDn + d) * (size_t)SKn + s;
      *(ushort4*)(Y + idx) = pk;
    }
  }
}

// ------------------------------------------- single-pass fused attention
// EXACT R9/R14 kernel (proven optimum of this structure: 325 us, spill-free,
// absmax 6.1e-5, occupancy 44%). Register bracket from R10/R11/R15: needs
// >102 <=128 unified regs; any lower budget spills (R10 -1.3GB, R11 -205MB),
// and off-loading p-hat to memory (R15) costs +800MB HBM traffic (+125us).
// Block (512 thr, 8 waves) owns one 16-row q-tile; wave w owns cols
// [256w,+256). Swapped mfma(K,Q) + krA permutation; no max-subtraction;
// p-hat packed bf16 in pf8[8]; unnormalized PV rescaled in epilogue.
__global__ __launch_bounds__(512)
__attribute__((amdgpu_waves_per_eu(4, 4)))
void fused_attn_kernel(
    const ushort_t* __restrict__ Qb, const ushort_t* __restrict__ Kb,
    const ushort_t* __restrict__ Vt, const unsigned* __restrict__ maskbits,
    float* __restrict__ attn_out, ushort_t* __restrict__ Ob)
{
  __shared__ float red[8][16];
  __shared__ float Opart[8][16][66];  // +2 pad kills bank conflicts

  const int bid = blockIdx.x;
  const int rt = (bid & 7) * 512 + (bid >> 3);  // XCD-chunked bijection
  const int wv = threadIdx.x >> 6;
  const int l  = threadIdx.x & 63;
  const int lr = l & 15, lg = l >> 4;
  const int bh = rt >> 7;
  const int q0 = (rt & 127) << 4;
  const int b  = bh >> 2, h = bh & 3;
  const int colbase = wv * 256;

  const ushort_t* Qh = Qb + (size_t)bh * SQn * HDn;
  const ushort_t* Kh = Kb + (size_t)bh * SKn * HDn;
  const ushort_t* Vh = Vt + (size_t)bh * HDn * SKn;

  short8 qa0 = *(const short8*)(Qh + (q0 + lr) * HDn + lg * 8);
  short8 qa1 = *(const short8*)(Qh + (q0 + lr) * HDn + 32 + lg * 8);

  const int krA = (lr >> 2) * 8 + (lr & 3);
  const unsigned* mrow = maskbits + ((size_t)b * SQn + q0 + lr) * (SKn / 32) + wv * 8;
  const int bsh = lg * 8;

  // ---- Phase A: QK^T once; packed p-hat + row-sum + unnormalized PV
  short8 pf8[8];
  float lsum = 0.f;
  f32x4 oacc[4];
  #pragma unroll
  for (int dt = 0; dt < 4; ++dt) oacc[dt] = (f32x4){0.f, 0.f, 0.f, 0.f};

  u32x4 mw = *(const u32x4*)mrow;   // second half loaded at s8==4
  #pragma unroll
  for (int s8 = 0; s8 < 8; ++s8) {
    if (s8 == 4) mw = *(const u32x4*)(mrow + 4);
    const int c = colbase + s8 * 32;
    const ushort_t* kp = Kh + (size_t)(c + krA) * HDn + lg * 8;
    short8 ka0 = *(const short8*)(kp);
    short8 ka1 = *(const short8*)(kp + 32);
    short8 kb0 = *(const short8*)(kp + 4 * HDn);
    short8 kb1 = *(const short8*)(kp + 4 * HDn + 32);
    f32x4 za = (f32x4){0.f, 0.f, 0.f, 0.f}, zb = (f32x4){0.f, 0.f, 0.f, 0.f};
    za = mfma16(ka0, qa0, za); za = mfma16(ka1, qa1, za);
    zb = mfma16(kb0, qa0, zb); zb = mfma16(kb1, qa1, zb);

    // V loads issued here: K regs dead, exp/pack VALU below hides latency
    const ushort_t* vp = Vh + (size_t)lr * SKn + c + lg * 8;
    short8 vb0 = *(const short8*)(vp);
    short8 vb1 = *(const short8*)(vp + 16 * SKn);
    short8 vb2 = *(const short8*)(vp + 32 * SKn);
    short8 vb3 = *(const short8*)(vp + 48 * SKn);

    const unsigned bits = (mw[s8 & 3] >> bsh) & 0xFFu;
    short8 pf;
    #pragma unroll
    for (int j = 0; j < 4; ++j) {
      float pa = ((bits >> j) & 1) ? fexp2(za[j] * SCALE2) : 0.f;
      float pb = ((bits >> (4 + j)) & 1) ? fexp2(zb[j] * SCALE2) : 0.f;
      lsum += pa + pb;
      pf[j] = (short)f2bf(pa);
      pf[4 + j] = (short)f2bf(pb);
    }
    pf8[s8] = pf;
    oacc[0] = mfma16(pf, vb0, oacc[0]);
    oacc[1] = mfma16(pf, vb1, oacc[1]);
    oacc[2] = mfma16(pf, vb2, oacc[2]);
    oacc[3] = mfma16(pf, vb3, oacc[3]);
  }

  // row-sum across the 4 lane-groups sharing row lr; stash partial O
  lsum += __shfl_xor(lsum, 16);
  lsum += __shfl_xor(lsum, 32);
  if (l < 16) red[wv][lr] = lsum;
  #pragma unroll
  for (int dt = 0; dt < 4; ++dt)
    #pragma unroll
    for (int r = 0; r < 4; ++r)
      Opart[wv][lg * 4 + r][dt * 16 + lr] = oacc[dt][r];
  __syncthreads();

  float gsum = 0.f;
  #pragma unroll
  for (int ww = 0; ww < 8; ++ww) gsum += red[ww][lr];
  const bool rowempty = (gsum == 0.f);   // fully-masked row (exact)
  const float rinv = rowempty ? 0.f : 1.f / gsum;

  // ---- Phase B: attn = bf16(p-hat) * rinv, plain cached stores
  float* arow = attn_out + ((size_t)bh * SQn + q0 + lr) * (size_t)SKn;
  #pragma unroll
  for (int s8 = 0; s8 < 8; ++s8) {
    const int c = colbase + s8 * 32;
    float av[8];
    #pragma unroll
    for (int j = 0; j < 8; ++j)
      av[j] = bf2f((unsigned short)pf8[s8][j]) * rinv;
    if (rowempty && s8 == 0 && wv == 0 && lg == 0) av[0] = 1.f;  // one-hot key 0
    *(f32x4*)(arow + c + lg * 8)     = (f32x4){av[0], av[1], av[2], av[3]};
    *(f32x4*)(arow + c + lg * 8 + 4) = (f32x4){av[4], av[5], av[6], av[7]};
  }

  // ---- epilogue: cross-wave O reduce, scale by 1/gsum per row
  #pragma unroll
  for (int e = threadIdx.x; e < 1024; e += 512) {
    const int row = e >> 6, d = e & 63;
    float gs = 0.f;
    #pragma unroll
    for (int ww = 0; ww < 8; ++ww) gs += red[ww][row];
    float s = 0.f;
    #pragma unroll
    for (int ww = 0; ww < 8; ++ww) s += Opart[ww][row][d];
    float val;
    if (gs == 0.f) {  // fully-masked row: attn=one-hot(key0) -> O=V[:,0]
      val = bf2f(Vh[(size_t)d * SKn]);
    } else {
      val = s / gs;
    }
    Ob[((size_t)b * SQn + q0 + row) * Hn + h * HDn + d] = f2bf(val);
  }
}

// ------------------------------------------------ output projection (bf16 A,W)
__global__ __launch_bounds__(256) void oproj_kernel(
    const unsigned short* __restrict__ A, const ushort_t* __restrict__ Wob,
    const float* __restrict__ bias, float* __restrict__ out)
{
  const int m0 = blockIdx.x * 64;
  const int n0 = blockIdx.y * 64;
  const int wv = threadIdx.x >> 6;
  const int l  = threadIdx.x & 63;
  const int lr = l & 15, lg = l >> 4;
  const int mrow = m0 + wv * 16 + lr;

  f32x4 acc[4];
  #pragma unroll
  for (int t = 0; t < 4; ++t) acc[t] = (f32x4){0.f, 0.f, 0.f, 0.f};

  for (int k0 = 0; k0 < Hn; k0 += 32) {
    short8 a = *(const short8*)(A + (size_t)mrow * Hn + k0 + lg * 8);
    #pragma unroll
    for (int t = 0; t < 4; ++t) {
      short8 bb = *(const short8*)(Wob + (size_t)(n0 + t * 16 + lr) * Hn + k0 + lg * 8);
      acc[t] = mfma16(a, bb, acc[t]);
    }
  }
  #pragma unroll
  for (int t = 0; t < 4; ++t) {
    const int n = n0 + t * 16 + lr;
    const float bv = bias[n];
    #pragma unroll
    for (int r = 0; r < 4; ++r) {
      const int m = m0 + wv * 16 + lg * 4 + r;
      out[(size_t)m * Hn + n] = acc[t][r] + bv;
    }
  }
}

extern "C" void kernel_launch(void* const* d_in, const int* in_sizes, int n_in,
                              void* d_out, int out_size, void* d_ws, size_t ws_size,
                              hipStream_t stream) {
  const float* query = (const float*)d_in[0];
  const float* key_  = (const float*)d_in[1];
  const float* value = (const float*)d_in[2];
  const void*  mask  = d_in[3];
  const float* Wq = (const float*)d_in[4];
  const float* bq = (const float*)d_in[5];
  const float* Wk = (const float*)d_in[6];
  const float* bk = (const float*)d_in[7];
  const float* Wv = (const float*)d_in[8];
  const float* bv = (const float*)d_in[9];
  const float* Wo = (const float*)d_in[10];
  const float* bo = (const float*)d_in[11];

  float* out  = (float*)d_out;
  float* attn = out + (size_t)Bn * SQn * Hn;

  char* ws = (char*)d_ws;
  unsigned short* Qb = (unsigned short*)ws;
  unsigned short* Kb = Qb + (size_t)Bn * SQn * Hn;
  unsigned short* Vt = Kb + (size_t)Bn * SKn * Hn;
  unsigned short* Ob = Vt + (size_t)Bn * SKn * Hn;
  unsigned* mbits = (unsigned*)(Ob + (size_t)Bn * SQn * Hn);     // 4 MiB
  ushort_t* Wb = (ushort_t*)(mbits + (size_t)Bn * SQn * (SKn / 32));  // 512 KiB
  // X bf16 scratch lives in the attn output region (24 MB of 536 MB):
  // written by prep, read by proj3, then overwritten by fused_attn_kernel
  // -- safe by stream ordering, deterministic under graph replay.
  ushort_t* Xb = (ushort_t*)attn;

  prep_kernel<<<1808, 256, 0, stream>>>(mask, Wq, Wk, Wv, Wo,
                                        query, key_, value,
                                        (ull_t*)mbits, Wb, Xb);
  proj3_kernel<<<dim3(256, 4, 3), 256, 0, stream>>>(
      Xb, Wb, bq, bk, bv, Qb, Kb, Vt);
  fused_attn_kernel<<<4096, 512, 0, stream>>>(Qb, Kb, Vt, mbits, attn, Ob);
  oproj_kernel<<<dim3(256, 4), 256, 0, stream>>>(Ob, Wb + 3 * 65536, bo, out);
}